// Round 7
// baseline (78.239 us; speedup 1.0000x reference)
//
#include <hip/hip_runtime.h>

// N-body all-pairs gravitational force, N=8192, fp32.
//
// Round-14: delete the partials pipeline. Confirmed model (r10/r13):
// nbody is VALU-issue-bound (2cyc/inst, packed fp32 works, ~7.5us);
// the OTHER controllable cost is the JSPLIT machinery: 6.3MB partial
// stores + 6.3MB reduce reads + an extra dispatch (~2us total).
// New structure: one wave owns IBLK=4 i's; its 64 lanes slice j.
//  - j staged in 2048-body SoA LDS tiles (32KB); lane-dependent
//    ds_read_b64 stride 8B = 2-way bank alias = free (m136).
//  - per-lane v2f accumulators; epilogue = 6-step __shfl_xor butterfly
//    (all-lanes-valid), lane 0 stores 12 floats. No d_ws use at all.
//  - grid 512 blocks x 4 waves = 2 waves/SIMD (r7: sufficient when
//    issue-bound); 32KB LDS -> 2 blocks/CU fits exactly.
//  - packed-j math identical to r13 (proven); only sum order changes.
// Prediction: dur 76.8 -> ~74-75.5, absmax ~0.125.
// If regression: revert to r13 + JSPLIT=32. If neutral: declare roofline
// (residual = 41us ws-poison fill + ~26us harness reset gaps, fixed).

constexpr int   NBODY   = 8192;
constexpr int   BLOCK   = 256;
constexpr int   IBLK    = 4;                   // i's per wave
constexpr int   IPB     = IBLK * 4;            // 16 i's per block (4 waves)
constexpr int   TILE    = 2048;                // j's per LDS tile
constexpr int   NTILE   = NBODY / TILE;        // 4
constexpr int   QITER   = TILE / 2 / 64;       // 16 j-pairs per lane per tile
constexpr float SOFT2   = 0.01f * 0.01f;

typedef float v2f __attribute__((ext_vector_type(2)));

__global__ __launch_bounds__(BLOCK, 2) void nbody_forces(
    const float* __restrict__ pos,       // [N,3]
    const float* __restrict__ mass,      // [N]
    float*       __restrict__ out)       // [N,3]
{
    const int tid  = threadIdx.x;
    const int lane = tid & 63;
    const int wv   = tid >> 6;
    const int iBase = blockIdx.x * IPB + wv * IBLK;

    // SoA j-tile as v2f so compute reads are naturally 8B-aligned b64.
    __shared__ v2f sx[TILE / 2], sy[TILE / 2], sz[TILE / 2], sm[TILE / 2];

    // Pre-negated i-coords, broadcast into both packed lanes.
    v2f mpx[IBLK], mpy[IBLK], mpz[IBLK];
    #pragma unroll
    for (int b = 0; b < IBLK; ++b) {
        const int i = iBase + b;
        const float x = pos[3 * i + 0], y = pos[3 * i + 1], z = pos[3 * i + 2];
        mpx[b] = (v2f){-x, -x};
        mpy[b] = (v2f){-y, -y};
        mpz[b] = (v2f){-z, -z};
    }
    const v2f soft2_2 = (v2f){SOFT2, SOFT2};

    v2f fx[IBLK], fy[IBLK], fz[IBLK];
    #pragma unroll
    for (int b = 0; b < IBLK; ++b) {
        fx[b] = (v2f){0.f, 0.f}; fy[b] = (v2f){0.f, 0.f}; fz[b] = (v2f){0.f, 0.f};
    }

    float* fsx = (float*)sx; float* fsy = (float*)sy;
    float* fsz = (float*)sz; float* fsm = (float*)sm;

    for (int t = 0; t < NTILE; ++t) {
        const int jb = t * TILE;
        __syncthreads();                 // prev-tile reads done before overwrite
        #pragma unroll
        for (int k = 0; k < TILE / BLOCK; ++k) {   // 8 j's per thread, coalesced-ish
            const int jl = tid + k * BLOCK;
            const int j  = jb + jl;
            fsx[jl] = pos[3 * j + 0];
            fsy[jl] = pos[3 * j + 1];
            fsz[jl] = pos[3 * j + 2];
            fsm[jl] = mass[j];
        }
        __syncthreads();

        #pragma unroll 4
        for (int q = 0; q < QITER; ++q) {
            const int p = lane + q * 64;           // pair index in tile
            const v2f x2 = sx[p];
            const v2f y2 = sy[p];
            const v2f z2 = sz[p];
            const v2f m2 = sm[p];
            #pragma unroll
            for (int b = 0; b < IBLK; ++b) {       // 4 i's share the 4 ds_reads
                const v2f dx = x2 + mpx[b];
                const v2f dy = y2 + mpy[b];
                const v2f dz = z2 + mpz[b];
                const v2f d2 = __builtin_elementwise_fma(dx, dx,
                               __builtin_elementwise_fma(dy, dy,
                               __builtin_elementwise_fma(dz, dz, soft2_2)));
                v2f inv;
                inv.x = __builtin_amdgcn_rsqf(d2.x);
                inv.y = __builtin_amdgcn_rsqf(d2.y);
                const v2f s = (m2 * inv) * (inv * inv);   // m * inv^3 (G = 1)
                fx[b] = __builtin_elementwise_fma(s, dx, fx[b]);
                fy[b] = __builtin_elementwise_fma(s, dy, fy[b]);
                fz[b] = __builtin_elementwise_fma(s, dz, fz[b]);
                // j == i: diff = 0 -> contribution 0, matches reference.
            }
        }
    }

    // Horizontal pack-sum, then 64-lane butterfly (all lanes end valid).
    float hx[IBLK], hy[IBLK], hz[IBLK];
    #pragma unroll
    for (int b = 0; b < IBLK; ++b) {
        hx[b] = fx[b].x + fx[b].y;
        hy[b] = fy[b].x + fy[b].y;
        hz[b] = fz[b].x + fz[b].y;
    }
    #pragma unroll
    for (int m = 1; m < 64; m <<= 1) {
        #pragma unroll
        for (int b = 0; b < IBLK; ++b) {
            hx[b] += __shfl_xor(hx[b], m);
            hy[b] += __shfl_xor(hy[b], m);
            hz[b] += __shfl_xor(hz[b], m);
        }
    }
    if (lane == 0) {
        #pragma unroll
        for (int b = 0; b < IBLK; ++b) {
            const int i = iBase + b;
            out[3 * i + 0] = hx[b];
            out[3 * i + 1] = hy[b];
            out[3 * i + 2] = hz[b];
        }
    }
}

extern "C" void kernel_launch(void* const* d_in, const int* in_sizes, int n_in,
                              void* d_out, int out_size, void* d_ws, size_t ws_size,
                              hipStream_t stream) {
    const float* pos  = (const float*)d_in[0];
    const float* mass = (const float*)d_in[1];
    float* out = (float*)d_out;
    (void)d_ws; (void)ws_size;

    nbody_forces<<<NBODY / IPB, BLOCK, 0, stream>>>(pos, mass, out);
}

// Round 8
// 77.430 us; speedup vs baseline: 1.0105x; 1.0105x over previous
//
#include <hip/hip_runtime.h>

// N-body all-pairs gravitational force, N=8192, fp32.
//
// Round-15: r13 structure (best: 76.8us) + IBLK=4 to amortize ds_reads.
// Calibrated model (r7-r14, 3 confirmed predictions):
//   dur ~= fill(~40, harness 256MiB ws-poison @85% HBM peak, fixed)
//        + reset-gaps(~26, fixed) + nbody(VALU-issue-bound) + partials(~2).
// r13: 4 uniform ds_read_b64 per kk-iter amortized over IBLK=2 -> 8
// insts/pair. IBLK=4 -> 60 insts/8 pairs = 7.5/pair (-6% nbody).
//  - BLOCK=256, IBLK=4 -> IBODIES=1024, grid (8,64) = 512 blocks
//    x 4 waves = 2 waves/SIMD (r7==r8: sufficient when issue-bound).
//  - JSPLIT=64, SoA LDS, packed v2f math, fp32 partials: all r13-proven.
// Prediction: nbody 7.5 -> ~7.0, dur 76.8 -> ~75.8-76.5, absmax 0.125.
// Pre-commit: next round declares ROOFLINE (residual levers < bench noise;
// kernel within ~10% of VALU-issue floor; 86% of dur is harness-fixed).

constexpr int   NBODY   = 8192;
constexpr int   BLOCK   = 256;
constexpr int   IBLK    = 4;
constexpr int   IBODIES = BLOCK * IBLK;        // 1024 i's per block
constexpr int   JSPLIT  = 64;
constexpr int   JPER    = NBODY / JSPLIT;      // 128 j's per block
constexpr float SOFT2   = 0.01f * 0.01f;
constexpr int   OUTE    = NBODY * 3;           // 24576

typedef float v2f __attribute__((ext_vector_type(2)));

__global__ __launch_bounds__(BLOCK, 4) void nbody_forces(
    const float* __restrict__ pos,       // [N,3]
    const float* __restrict__ mass,      // [N]
    float*       __restrict__ part)      // [JSPLIT][N*3] partials
{
    const int tid   = threadIdx.x;
    const int iBase = blockIdx.x * IBODIES + tid;
    const int j0    = blockIdx.y * JPER;

    // SoA LDS tile: uniform-address b64 reads give {v_j0, v_j1} pairs.
    __shared__ float shx[JPER], shy[JPER], shz[JPER], shm[JPER];
    if (tid < JPER) {
        const int j = j0 + tid;
        shx[tid] = pos[3 * j + 0];
        shy[tid] = pos[3 * j + 1];
        shz[tid] = pos[3 * j + 2];
        shm[tid] = mass[j];
    }

    // Pre-negated i-coords, broadcast into both lanes: dx = xj + (-xi).
    v2f mpx[IBLK], mpy[IBLK], mpz[IBLK];
    #pragma unroll
    for (int b = 0; b < IBLK; ++b) {
        const int i = iBase + b * BLOCK;
        const float x = pos[3 * i + 0], y = pos[3 * i + 1], z = pos[3 * i + 2];
        mpx[b] = (v2f){-x, -x};
        mpy[b] = (v2f){-y, -y};
        mpz[b] = (v2f){-z, -z};
    }
    const v2f soft2_2 = (v2f){SOFT2, SOFT2};
    __syncthreads();

    v2f fx[IBLK], fy[IBLK], fz[IBLK];
    #pragma unroll
    for (int b = 0; b < IBLK; ++b) {
        fx[b] = (v2f){0.f, 0.f}; fy[b] = (v2f){0.f, 0.f}; fz[b] = (v2f){0.f, 0.f};
    }

    #pragma unroll 4
    for (int kk = 0; kk < JPER / 2; ++kk) {
        const v2f x2 = *reinterpret_cast<const v2f*>(&shx[2 * kk]);
        const v2f y2 = *reinterpret_cast<const v2f*>(&shy[2 * kk]);
        const v2f z2 = *reinterpret_cast<const v2f*>(&shz[2 * kk]);
        const v2f m2 = *reinterpret_cast<const v2f*>(&shm[2 * kk]);
        #pragma unroll
        for (int b = 0; b < IBLK; ++b) {   // 4 reads amortized over 4 chains
            const v2f dx = x2 + mpx[b];
            const v2f dy = y2 + mpy[b];
            const v2f dz = z2 + mpz[b];
            const v2f d2 = __builtin_elementwise_fma(dx, dx,
                           __builtin_elementwise_fma(dy, dy,
                           __builtin_elementwise_fma(dz, dz, soft2_2)));
            v2f inv;
            inv.x = __builtin_amdgcn_rsqf(d2.x);    // v_rsq_f32 (~free, r10)
            inv.y = __builtin_amdgcn_rsqf(d2.y);
            const v2f s = (m2 * inv) * (inv * inv); // m * inv^3  (G = 1)
            fx[b] = __builtin_elementwise_fma(s, dx, fx[b]);
            fy[b] = __builtin_elementwise_fma(s, dy, fy[b]);
            fz[b] = __builtin_elementwise_fma(s, dz, fz[b]);
            // j == i: diff = 0 -> contribution 0, matches reference.
        }
    }

    float* dst = part + (size_t)blockIdx.y * OUTE;
    #pragma unroll
    for (int b = 0; b < IBLK; ++b) {
        const int i = iBase + b * BLOCK;
        dst[3 * i + 0] = fx[b].x + fx[b].y;
        dst[3 * i + 1] = fy[b].x + fy[b].y;
        dst[3 * i + 2] = fz[b].x + fz[b].y;
    }
}

__global__ __launch_bounds__(256) void reduce_kernel(
    const float* __restrict__ part,      // [JSPLIT][OUTE]
    float*       __restrict__ out)       // [OUTE]
{
    const int e = blockIdx.x * blockDim.x + threadIdx.x;   // 0..OUTE-1
    float s = 0.f;
    #pragma unroll 8
    for (int k = 0; k < JSPLIT; ++k)
        s += part[(size_t)k * OUTE + e];
    out[e] = s;
}

extern "C" void kernel_launch(void* const* d_in, const int* in_sizes, int n_in,
                              void* d_out, int out_size, void* d_ws, size_t ws_size,
                              hipStream_t stream) {
    const float* pos  = (const float*)d_in[0];
    const float* mass = (const float*)d_in[1];
    float* out = (float*)d_out;

    float* part = (float*)d_ws;          // [JSPLIT][OUTE] = 6.3 MB

    dim3 grid(NBODY / IBODIES, JSPLIT);  // (8, 64) = 512 blocks
    nbody_forces<<<grid, BLOCK, 0, stream>>>(pos, mass, part);

    reduce_kernel<<<OUTE / 256, 256, 0, stream>>>(part, out);
}